// Round 1
// baseline (39.829 us; speedup 1.0000x reference)
//
#include <hip/hip_runtime.h>

typedef __attribute__((ext_vector_type(8))) short short8;
typedef __attribute__((ext_vector_type(4))) float f32x4;

#define DI __device__ __forceinline__

namespace {
constexpr int F_   = 64;
constexpr int D_   = 32;
constexpr int H_   = 64;
constexpr int CM_  = 32;
constexpr int TOT_ = 512;
constexpr int BT_  = 256;   // batch rows per block
constexpr int NB_  = (16384 / BT_) * F_;  // 4096 blocks
}

DI unsigned short f2bf(float v) {
    __bf16 h = (__bf16)v;                      // RNE convert, compiler can pk-fuse
    return __builtin_bit_cast(unsigned short, h);
}

__global__ __launch_bounds__(256)
void recon_kernel(const float* __restrict__ x, const float* __restrict__ W1,
                  const float* __restrict__ b1, const float* __restrict__ W2,
                  const float* __restrict__ b2, float* __restrict__ out)
{
    // LDS: transposed bf16 weights + per-wave h staging tile (swizzled)
    __shared__ __align__(16) unsigned short w1t[H_ * D_];    // [n<64][k<32]
    __shared__ __align__(16) unsigned short w2t[CM_ * H_];   // [n<32][k<64]
    __shared__ __align__(16) unsigned short hb[4][16 * H_];  // 2 KB per wave

    // XCD-aware remap: XCD x owns batch-tiles [x*8, x*8+8) x all 64 features,
    // so all writers of an output row share one XCD's L2 (writes merge).
    const int bid   = blockIdx.x;               // 0..4095
    const int f     = (bid >> 3) & 63;
    const int btile = ((bid & 7) << 3) | (bid >> 9);

    const int tid  = threadIdx.x;
    const int lane = tid & 63;
    const int wv   = tid >> 6;
    const int l15  = lane & 15;
    const int kg   = lane >> 4;

    // ---- stage W1^T and W2^T into LDS as bf16 (once per block) ----
    {
        const int e0 = tid * 8;                 // 256 thr x 8 = 2048 elements
        const float* W1f = W1 + f * (D_ * H_);
        const float* W2f = W2 + f * (H_ * CM_);
        f32x4 v0 = *(const f32x4*)(W1f + e0);
        f32x4 v1 = *(const f32x4*)(W1f + e0 + 4);
        f32x4 u0 = *(const f32x4*)(W2f + e0);
        f32x4 u1 = *(const f32x4*)(W2f + e0 + 4);
#pragma unroll
        for (int j = 0; j < 8; ++j) {
            int e = e0 + j;
            float v = (j < 4) ? v0[j] : v1[j - 4];
            w1t[(e & 63) * D_ + (e >> 6)] = f2bf(v);   // W1: e = k*64 + n
            float u = (j < 4) ? u0[j] : u1[j - 4];
            w2t[(e & 31) * H_ + (e >> 5)] = f2bf(u);   // W2: e = k*32 + n
        }
    }
    __syncthreads();

    // ---- hoist B-fragments into registers (invariant across batch tiles) ----
    short8 w1b[4];                               // GEMM1 B: n-tiles 0..3 (H=64)
#pragma unroll
    for (int nt = 0; nt < 4; ++nt)
        w1b[nt] = *(const short8*)&w1t[(nt * 16 + l15) * D_ + kg * 8];

    short8 w2b[2][2];                            // GEMM2 B: [n-tile][k-step]
#pragma unroll
    for (int nt = 0; nt < 2; ++nt)
#pragma unroll
        for (int ks = 0; ks < 2; ++ks)
            w2b[nt][ks] = *(const short8*)&w2t[(nt * 16 + l15) * H_ + ks * 32 + kg * 8];

    float b1v[4], b2v[2];
#pragma unroll
    for (int nt = 0; nt < 4; ++nt) b1v[nt] = b1[f * H_ + nt * 16 + l15];
#pragma unroll
    for (int nt = 0; nt < 2; ++nt) b2v[nt] = b2[f * CM_ + nt * 16 + l15];

    // output gather params (CARDS = [4,8,16,32]*8 ++ [1]*32)
    int card, off;
    if (f < 32) { card = 4 << (f & 3); off = (f >> 2) * 60 + card - 4; }
    else        { card = 1;            off = 480 + (f - 32); }

    unsigned short* hw = hb[wv];
    const f32x4 zero = {0.f, 0.f, 0.f, 0.f};
    const int b0 = btile * BT_ + wv * 64;

#pragma unroll
    for (int t = 0; t < 4; ++t) {
        const int rbase = b0 + t * 16;

        // GEMM1 A-fragment straight from global: row = l15, k = kg*8..kg*8+7
        const float* xr = x + (size_t)(rbase + l15) * (F_ * D_) + f * D_ + kg * 8;
        f32x4 a0 = *(const f32x4*)xr;
        f32x4 a1 = *(const f32x4*)(xr + 4);
        short8 af;
#pragma unroll
        for (int j = 0; j < 4; ++j) {
            af[j]     = (short)f2bf(a0[j]);
            af[4 + j] = (short)f2bf(a1[j]);
        }

        // GEMM1: h[16x64] = x[16x32] @ W1[32x64]   (K=32 = one MFMA step)
        f32x4 c1[4];
#pragma unroll
        for (int nt = 0; nt < 4; ++nt)
            c1[nt] = __builtin_amdgcn_mfma_f32_16x16x32_bf16(af, w1b[nt], zero, 0, 0, 0);

        // bias + ReLU -> bf16 -> wave-private swizzled LDS (no barrier needed)
#pragma unroll
        for (int nt = 0; nt < 4; ++nt) {
#pragma unroll
            for (int j = 0; j < 4; ++j) {
                int r = kg * 4 + j;
                int c = nt * 16 + l15;
                float v = c1[nt][j] + b1v[nt];
                v = v > 0.f ? v : 0.f;
                int idx = (r * H_ + c) ^ ((r & 7) << 3);   // XOR-swizzle (16B granule)
                hw[idx] = f2bf(v);
            }
        }

        // GEMM2 A-fragments from swizzled LDS: row = l15, k = ks*32 + kg*8
        short8 ha[2];
#pragma unroll
        for (int ks = 0; ks < 2; ++ks) {
            int idx = (l15 * H_ + ks * 32 + kg * 8) ^ ((l15 & 7) << 3);
            ha[ks] = *(const short8*)&hw[idx];
        }

        // GEMM2: out[16x32] = h[16x64] @ W2[64x32]; skip n-tile 1 unless card==32
        f32x4 c2[2];
        c2[0] = __builtin_amdgcn_mfma_f32_16x16x32_bf16(ha[0], w2b[0][0], zero, 0, 0, 0);
        c2[0] = __builtin_amdgcn_mfma_f32_16x16x32_bf16(ha[1], w2b[0][1], c2[0], 0, 0, 0);
        if (card == 32) {
            c2[1] = __builtin_amdgcn_mfma_f32_16x16x32_bf16(ha[0], w2b[1][0], zero, 0, 0, 0);
            c2[1] = __builtin_amdgcn_mfma_f32_16x16x32_bf16(ha[1], w2b[1][1], c2[1], 0, 0, 0);
        }

        // gathered store: out[row][off + c] for c < card
        const int ntiles = (card == 32) ? 2 : 1;
        for (int nt = 0; nt < ntiles; ++nt) {
            int c = nt * 16 + l15;
            if (c < card) {
                float bias = b2v[nt];
#pragma unroll
                for (int j = 0; j < 4; ++j) {
                    int row = rbase + kg * 4 + j;
                    out[(size_t)row * TOT_ + off + c] = c2[nt][j] + bias;
                }
            }
        }
    }
}

extern "C" void kernel_launch(void* const* d_in, const int* in_sizes, int n_in,
                              void* d_out, int out_size, void* d_ws, size_t ws_size,
                              hipStream_t stream) {
    const float* x  = (const float*)d_in[0];
    const float* W1 = (const float*)d_in[1];
    const float* b1 = (const float*)d_in[2];
    const float* W2 = (const float*)d_in[3];
    const float* b2 = (const float*)d_in[4];
    float* out = (float*)d_out;
    recon_kernel<<<NB_, 256, 0, stream>>>(x, W1, b1, W2, b2, out);
}